// Round 3
// baseline (989.366 us; speedup 1.0000x reference)
//
#include <hip/hip_runtime.h>
#include <hip/hip_bf16.h>
#include <stdint.h>

typedef unsigned short u16;
typedef unsigned int u32;
typedef __attribute__((ext_vector_type(4))) float f32x4;
typedef __attribute__((ext_vector_type(4))) int i32x4;
typedef __attribute__((ext_vector_type(8))) u16 u16x8;
typedef __attribute__((ext_vector_type(8))) __bf16 bf16x8;

constexpr int BATCH = 4096, DIN = 1024, DH = 4096, DOUT = 1024, NEXP = 8;

struct Ptr4 { float* p[4]; };

__device__ __forceinline__ u16 f2bf(float f) {
  u32 u = __float_as_uint(f);
  u += 0x7fffu + ((u >> 16) & 1u);   // RNE (finite values only here)
  return (u16)(u >> 16);
}

// global -> LDS direct copy, 16B per lane. LDS dest must be wave-uniform base;
// HW adds lane*16.
#define GLOAD_LDS16(gp, lp)                                                    \
  __builtin_amdgcn_global_load_lds(                                           \
      (__attribute__((address_space(1))) void*)(gp),                          \
      (__attribute__((address_space(3))) void*)(lp), 16, 0, 0)

// ---------------------------------------------------------------------------
// Gate: scores = (x @ gate_w + gate_b)/e, softmax, top-5 mask, renorm.
// One wave per row.
__global__ void gate_kernel(const float* __restrict__ x,
                            const float* __restrict__ gw,
                            const float* __restrict__ gb,
                            float* __restrict__ wgt) {
  const int wave = threadIdx.x >> 6, lane = threadIdx.x & 63;
  const int b = blockIdx.x * 4 + wave;
  const float* xr = x + (size_t)b * DIN;
  float acc[NEXP];
#pragma unroll
  for (int e = 0; e < NEXP; ++e) acc[e] = 0.f;
  for (int k = lane; k < DIN; k += 64) {
    const float xv = xr[k];
    const f32x4 g0 = *(const f32x4*)(gw + (size_t)k * NEXP);
    const f32x4 g1 = *(const f32x4*)(gw + (size_t)k * NEXP + 4);
    acc[0] += xv * g0[0]; acc[1] += xv * g0[1];
    acc[2] += xv * g0[2]; acc[3] += xv * g0[3];
    acc[4] += xv * g1[0]; acc[5] += xv * g1[1];
    acc[6] += xv * g1[2]; acc[7] += xv * g1[3];
  }
#pragma unroll
  for (int off = 32; off; off >>= 1)
#pragma unroll
    for (int e = 0; e < NEXP; ++e) acc[e] += __shfl_xor(acc[e], off);
  if (lane == 0) {
    const float invT = 0.36787944117144233f;  // 1/e
    float s[NEXP], mx = -1e30f;
    for (int e = 0; e < NEXP; ++e) { s[e] = (acc[e] + gb[e]) * invT; mx = fmaxf(mx, s[e]); }
    float p[NEXP], sum = 0.f;
    for (int e = 0; e < NEXP; ++e) { p[e] = expf(s[e] - mx); sum += p[e]; }
    const float inv = 1.f / sum;
    for (int e = 0; e < NEXP; ++e) p[e] *= inv;
    float w[NEXP], wsum = 0.f;
    for (int e = 0; e < NEXP; ++e) {
      int cnt = 0;
      for (int j = 0; j < NEXP; ++j) cnt += (p[j] > p[e]) || (p[j] == p[e] && j < e);
      w[e] = (cnt < 5) ? p[e] : 0.f;   // top-5 of 8, first-occurrence tie-break
      wsum += w[e];
    }
    const float inv2 = 1.f / (wsum + 1e-8f);
    for (int e = 0; e < NEXP; ++e) wgt[(size_t)b * NEXP + e] = w[e] * inv2;
  }
}

// ---------------------------------------------------------------------------
// fp32 -> bf16 elementwise (x matrix)
__global__ void cvt_bf16(const float* __restrict__ src, u16* __restrict__ dst, int n) {
  const int i = (blockIdx.x * 256 + threadIdx.x) * 8;
  if (i >= n) return;
  const f32x4 a = *(const f32x4*)(src + i);
  const f32x4 b = *(const f32x4*)(src + i + 4);
  u16x8 o;
  o[0] = f2bf(a[0]); o[1] = f2bf(a[1]); o[2] = f2bf(a[2]); o[3] = f2bf(a[3]);
  o[4] = f2bf(b[0]); o[5] = f2bf(b[1]); o[6] = f2bf(b[2]); o[7] = f2bf(b[3]);
  *(u16x8*)(dst + i) = o;
}

// ---------------------------------------------------------------------------
// Transpose + convert: per slice z, dst[(c)*ldd + r] = bf16(src[r*C + c]).
// dst slice offset = (z>>2)*dst_hi + (z&3)*dst_lo.
__global__ void transpose_cvt(const float* __restrict__ src, u16* __restrict__ dst,
                              int C, int ldd, size_t src_slice,
                              size_t dst_hi, size_t dst_lo) {
  __shared__ float ts[32][33];
  const int z = blockIdx.z;
  const float* s = src + (size_t)z * src_slice;
  u16* d = dst + (size_t)(z >> 2) * dst_hi + (size_t)(z & 3) * dst_lo;
  const int c0 = blockIdx.x * 32, r0 = blockIdx.y * 32;
  const int tc = threadIdx.x & 31, tr = threadIdx.x >> 5;
#pragma unroll
  for (int p = 0; p < 4; ++p)
    ts[tr + p * 8][tc] = s[(size_t)(r0 + tr + p * 8) * C + c0 + tc];
  __syncthreads();
#pragma unroll
  for (int p = 0; p < 4; ++p) {
    const int cl = tr + p * 8;
    d[(size_t)(c0 + cl) * ldd + r0 + tc] = f2bf(ts[tc][cl]);
  }
}

// ---------------------------------------------------------------------------
// GEMM C[M,N] = A[M,K] * Bt[N,K]^T  (both operands K-contiguous, bf16, fp32 acc)
// 256 threads, 4 waves in 2x2, 16x16x32 bf16 MFMA, BK=64, m97 structure.
// EPI=0 (layer1): C -> relu(C + b1[expert][col]) * wgt[row][expert] -> bf16 Hs
//                 (blockIdx.z = expert slot within camp)
// EPI=2 (layer2 split-K by expert): blockIdx.z = expert slot; A/Bt offset by
//                 z*DH along K; fp32 partial to parts.p[z].
template <int BM, int BN, int EPI>
__global__ __launch_bounds__(256, 2) void gemm_bt(
    const u16* __restrict__ A0, int lda,
    const u16* __restrict__ Bt0, int ldb, int K,
    u16* __restrict__ dstH0, Ptr4 parts,
    const float* __restrict__ wgt, const float* __restrict__ bias0, int camp) {
  constexpr int WM = BM / 2, WN = BN / 2, MR = WM / 16, NR = WN / 16;
  __shared__ __align__(16) u16 sA[BM * 64];
  __shared__ __align__(16) u16 sB[BN * 64];

  const int tid = threadIdx.x, wave = tid >> 6, lane = tid & 63;
  const int wr = wave >> 1, wc = wave & 1, lh = lane >> 4, l15 = lane & 15;
  const int bN = blockIdx.x * BN, bM = blockIdx.y * BM;
  const int z = blockIdx.z;

  const u16* A = A0;
  const u16* Bt = Bt0;
  const float* bias = bias0;
  u16* dstH = dstH0;
  int expert = 0;
  if (EPI == 0) {
    expert = camp * 4 + z;
    Bt = Bt0 + (size_t)expert * DH * DIN;
    bias = bias0 + (size_t)expert * DH;
    dstH = dstH0 + (size_t)z * DH;
  } else {
    A = A0 + (size_t)z * DH;     // Hs[row][z*DH + k]
    Bt = Bt0 + (size_t)z * DH;   // w2t[o][z*DH + h]
  }

  const int srow = tid >> 3, scol = (tid & 7) * 8;
  f32x4 acc[MR][NR] = {};

  for (int kt = 0; kt < K; kt += 64) {
    __syncthreads();
#pragma unroll
    for (int i = 0; i < BM / 32; ++i)
      GLOAD_LDS16(A + (size_t)(bM + i * 32 + srow) * lda + kt + scol,
                  sA + (i * 256 + wave * 64) * 8);
#pragma unroll
    for (int i = 0; i < BN / 32; ++i)
      GLOAD_LDS16(Bt + (size_t)(bN + i * 32 + srow) * ldb + kt + scol,
                  sB + (i * 256 + wave * 64) * 8);
    __syncthreads();
#pragma unroll
    for (int kk = 0; kk < 2; ++kk) {
      const int ko = kk * 32 + lh * 8;
      bf16x8 af[MR], bfv[NR];
#pragma unroll
      for (int m = 0; m < MR; ++m)
        af[m] = __builtin_bit_cast(
            bf16x8, *(const i32x4*)(sA + (wr * WM + m * 16 + l15) * 64 + ko));
#pragma unroll
      for (int n = 0; n < NR; ++n)
        bfv[n] = __builtin_bit_cast(
            bf16x8, *(const i32x4*)(sB + (wc * WN + n * 16 + l15) * 64 + ko));
#pragma unroll
      for (int m = 0; m < MR; ++m)
#pragma unroll
        for (int n = 0; n < NR; ++n)
          acc[m][n] = __builtin_amdgcn_mfma_f32_16x16x32_bf16(af[m], bfv[n],
                                                              acc[m][n], 0, 0, 0);
    }
  }

  // Epilogue. C/D layout: col = lane&15, row = (lane>>4)*4 + r  [m89-verified]
  if (EPI == 0) {
#pragma unroll
    for (int m = 0; m < MR; ++m)
#pragma unroll
      for (int r = 0; r < 4; ++r) {
        const int row = bM + wr * WM + m * 16 + lh * 4 + r;
        const float wsc = wgt[(size_t)row * NEXP + expert];
#pragma unroll
        for (int n = 0; n < NR; ++n) {
          const int col = bN + wc * WN + n * 16 + l15;
          float v = acc[m][n][r] + bias[col];
          v = fmaxf(v, 0.0f) * wsc;
          dstH[(size_t)row * (4 * DH) + col] = f2bf(v);
        }
      }
  } else {
    float* __restrict__ P = parts.p[z];
#pragma unroll
    for (int m = 0; m < MR; ++m)
#pragma unroll
      for (int r = 0; r < 4; ++r) {
        const int row = bM + wr * WM + m * 16 + lh * 4 + r;
#pragma unroll
        for (int n = 0; n < NR; ++n) {
          const int col = bN + wc * WN + n * 16 + l15;
          P[(size_t)row * DOUT + col] = acc[m][n][r];
        }
      }
  }
}

// ---------------------------------------------------------------------------
// Reduce 4 split-K partials + weight-folded b2 bias -> dst (may alias p0).
__global__ void reduce_kernel(float* __restrict__ dst,
                              const float* __restrict__ p0, const float* __restrict__ p1,
                              const float* __restrict__ p2, const float* __restrict__ p3,
                              const float* __restrict__ wgt,
                              const float* __restrict__ b2c, int camp) {
  const int b = blockIdx.x, t = threadIdx.x;
  const f32x4 wv = *(const f32x4*)(wgt + (size_t)b * NEXP + camp * 4);
  const size_t ro = (size_t)b * DOUT;
#pragma unroll
  for (int j = 0; j < 4; ++j) {
    const int i = j * 256 + t;
    const float bias = wv[0] * b2c[i] + wv[1] * b2c[DOUT + i] +
                       wv[2] * b2c[2 * DOUT + i] + wv[3] * b2c[3 * DOUT + i];
    dst[ro + i] = p0[ro + i] + p1[ro + i] + p2[ro + i] + p3[ro + i] + bias;
  }
}

// ---------------------------------------------------------------------------
// Final: repulsion = out_a - out_g; ph_corr = 2*sigmoid(alpha*l2*(1+var)+beta);
// output = repulsion * ph_corr. One block per row.
__global__ void final_kernel(float* __restrict__ out,
                             const float* __restrict__ alpha,
                             const float* __restrict__ beta) {
  const int b = blockIdx.x, t = threadIdx.x;
  const float* pa = out + (size_t)BATCH * DOUT + (size_t)b * DOUT;
  const float* pg = out + (size_t)2 * BATCH * DOUT + (size_t)b * DOUT;
  float* po = out + (size_t)b * DOUT;
  float d[4], s1 = 0.f, s2 = 0.f;
#pragma unroll
  for (int j = 0; j < 4; ++j) {
    const int i = j * 256 + t;
    d[j] = pa[i] - pg[i];
    s1 += d[j];
    s2 += d[j] * d[j];
  }
#pragma unroll
  for (int off = 32; off; off >>= 1) {
    s1 += __shfl_xor(s1, off);
    s2 += __shfl_xor(s2, off);
  }
  __shared__ float r1[4], r2[4];
  if ((t & 63) == 0) { r1[t >> 6] = s1; r2[t >> 6] = s2; }
  __syncthreads();
  s1 = r1[0] + r1[1] + r1[2] + r1[3];
  s2 = r2[0] + r2[1] + r2[2] + r2[3];
  const float mean = s1 * (1.f / DOUT);
  const float var = s2 * (1.f / DOUT) - mean * mean;  // population var
  const float dist = sqrtf(s2) * (1.f + var);
  const float zz = alpha[0] * dist + beta[0];
  const float corr = 2.f / (1.f + expf(-zz));
#pragma unroll
  for (int j = 0; j < 4; ++j) po[j * 256 + t] = d[j] * corr;
}

// ---------------------------------------------------------------------------
extern "C" void kernel_launch(void* const* d_in, const int* in_sizes, int n_in,
                              void* d_out, int out_size, void* d_ws, size_t ws_size,
                              hipStream_t stream) {
  const float* x   = (const float*)d_in[0];
  const float* gw  = (const float*)d_in[1];
  const float* gb  = (const float*)d_in[2];
  const float* w1  = (const float*)d_in[3];
  const float* b1  = (const float*)d_in[4];
  const float* w2  = (const float*)d_in[5];
  const float* b2  = (const float*)d_in[6];
  const float* pha = (const float*)d_in[7];
  const float* phb = (const float*)d_in[8];
  float* out = (float*)d_out;  // [output | out_a | out_g], each BATCH*DOUT f32
  float* out_a = out + (size_t)BATCH * DOUT;
  float* out_g = out + (size_t)2 * BATCH * DOUT;

  // Workspace layout (264.125 MiB total, same footprint as round 1):
  //   wgt 128KB | xb 8MB | w1t 64MB (first 32MB reused as w2t1 after camp0 L1)
  //   | w2t0 32MB | P0 16MB | P1 16MB | Hs 128MB
  char* ws = (char*)d_ws;
  float* wgt = (float*)ws;
  u16* xb   = (u16*)(ws + 131072);
  u16* w1t  = (u16*)(ws + 8519680);
  u16* w2t1 = w1t;  // recycled after camp0 layer-1
  u16* w2t0 = (u16*)(ws + 75628544);
  float* P0 = (float*)(ws + 109182976);
  float* P1 = (float*)(ws + 125960192);
  u16* Hs   = (u16*)(ws + 142737408);

  gate_kernel<<<BATCH / 4, 256, 0, stream>>>(x, gw, gb, wgt);
  cvt_bf16<<<(BATCH * DIN / 8) / 256, 256, 0, stream>>>(x, xb, BATCH * DIN);
  // w1[e][k=1024][n=4096] -> w1t[e][n][k], ldd=DIN
  transpose_cvt<<<dim3(DH / 32, DIN / 32, NEXP), 256, 0, stream>>>(
      w1, w1t, DH, DIN, (size_t)DIN * DH, (size_t)4 * DH * DIN, (size_t)DH * DIN);
  // w2 camp0: w2[e][h=4096][n=1024] -> w2t0[n][e_local*DH + h], ldd=4*DH
  transpose_cvt<<<dim3(DOUT / 32, DH / 32, 4), 256, 0, stream>>>(
      w2, w2t0, DOUT, 4 * DH, (size_t)DH * DOUT, 0, (size_t)DH);

  Ptr4 parts0 = {{out_a, out, out_g, P0}};
  Ptr4 parts1 = {{out_g, out, P0, P1}};
  Ptr4 dummy = {{nullptr, nullptr, nullptr, nullptr}};

  // ---- camp 0 ----
  gemm_bt<128, 128, 0><<<dim3(DH / 128, BATCH / 128, 4), 256, 0, stream>>>(
      xb, DIN, w1t, DIN, DIN, Hs, dummy, wgt, b1, 0);
  // w2 camp1 transpose into the now-dead w1t[0..3] region
  transpose_cvt<<<dim3(DOUT / 32, DH / 32, 4), 256, 0, stream>>>(
      w2 + (size_t)4 * DH * DOUT, w2t1, DOUT, 4 * DH, (size_t)DH * DOUT, 0, (size_t)DH);
  gemm_bt<128, 128, 2><<<dim3(DOUT / 128, BATCH / 128, 4), 256, 0, stream>>>(
      Hs, 4 * DH, w2t0, 4 * DH, DH, nullptr, parts0, nullptr, nullptr, 0);
  reduce_kernel<<<BATCH, 256, 0, stream>>>(out_a, out_a, out, out_g, P0,
                                           wgt, b2, 0);
  // ---- camp 1 ----
  gemm_bt<128, 128, 0><<<dim3(DH / 128, BATCH / 128, 4), 256, 0, stream>>>(
      xb, DIN, w1t, DIN, DIN, Hs, dummy, wgt, b1, 1);
  gemm_bt<128, 128, 2><<<dim3(DOUT / 128, BATCH / 128, 4), 256, 0, stream>>>(
      Hs, 4 * DH, w2t1, 4 * DH, DH, nullptr, parts1, nullptr, nullptr, 1);
  reduce_kernel<<<BATCH, 256, 0, stream>>>(out_g, out_g, out, P0, P1,
                                           wgt, b2 + (size_t)4 * DOUT, 1);

  final_kernel<<<BATCH, 256, 0, stream>>>(out, pha, phb);
}

// Round 4
// 713.337 us; speedup vs baseline: 1.3870x; 1.3870x over previous
//
#include <hip/hip_runtime.h>
#include <hip/hip_bf16.h>
#include <stdint.h>

typedef unsigned short u16;
typedef unsigned int u32;
typedef __attribute__((ext_vector_type(4))) float f32x4;
typedef __attribute__((ext_vector_type(4))) int i32x4;
typedef __attribute__((ext_vector_type(8))) u16 u16x8;
typedef __attribute__((ext_vector_type(8))) __bf16 bf16x8;

constexpr int BATCH = 4096, DIN = 1024, DH = 4096, DOUT = 1024, NEXP = 8;

struct Ptr4 { float* p[4]; };

__device__ __forceinline__ u16 f2bf(float f) {
  u32 u = __float_as_uint(f);
  u += 0x7fffu + ((u >> 16) & 1u);   // RNE (finite values only here)
  return (u16)(u >> 16);
}

// global -> LDS direct copy, 16B per lane. LDS dest is wave-uniform base;
// HW adds lane*16.
#define GLOAD_LDS16(gp, lp)                                                    \
  __builtin_amdgcn_global_load_lds(                                           \
      (__attribute__((address_space(1))) void*)(gp),                          \
      (__attribute__((address_space(3))) void*)(lp), 16, 0, 0)

#define BAR()                                                                  \
  { asm volatile("" ::: "memory"); __builtin_amdgcn_s_barrier();               \
    asm volatile("" ::: "memory"); }
#define VM4() asm volatile("s_waitcnt vmcnt(4)" ::: "memory")
#define VM0() asm volatile("s_waitcnt vmcnt(0)" ::: "memory")

// stage one half-tile (2 x 64-row chunks, 8KB each across 8 waves)
#define ST2(dst, src, ld)                                                      \
  { GLOAD_LDS16((src), (dst));                                                 \
    GLOAD_LDS16((src) + (size_t)64 * (ld), (dst) + 4096); }

// ---------------------------------------------------------------------------
// Gate: scores = (x @ gate_w + gate_b)/e, softmax, top-5 mask, renorm.
__global__ void gate_kernel(const float* __restrict__ x,
                            const float* __restrict__ gw,
                            const float* __restrict__ gb,
                            float* __restrict__ wgt) {
  const int wave = threadIdx.x >> 6, lane = threadIdx.x & 63;
  const int b = blockIdx.x * 4 + wave;
  const float* xr = x + (size_t)b * DIN;
  float acc[NEXP];
#pragma unroll
  for (int e = 0; e < NEXP; ++e) acc[e] = 0.f;
  for (int k = lane; k < DIN; k += 64) {
    const float xv = xr[k];
    const f32x4 g0 = *(const f32x4*)(gw + (size_t)k * NEXP);
    const f32x4 g1 = *(const f32x4*)(gw + (size_t)k * NEXP + 4);
    acc[0] += xv * g0[0]; acc[1] += xv * g0[1];
    acc[2] += xv * g0[2]; acc[3] += xv * g0[3];
    acc[4] += xv * g1[0]; acc[5] += xv * g1[1];
    acc[6] += xv * g1[2]; acc[7] += xv * g1[3];
  }
#pragma unroll
  for (int off = 32; off; off >>= 1)
#pragma unroll
    for (int e = 0; e < NEXP; ++e) acc[e] += __shfl_xor(acc[e], off);
  if (lane == 0) {
    const float invT = 0.36787944117144233f;  // 1/e
    float s[NEXP], mx = -1e30f;
    for (int e = 0; e < NEXP; ++e) { s[e] = (acc[e] + gb[e]) * invT; mx = fmaxf(mx, s[e]); }
    float p[NEXP], sum = 0.f;
    for (int e = 0; e < NEXP; ++e) { p[e] = expf(s[e] - mx); sum += p[e]; }
    const float inv = 1.f / sum;
    for (int e = 0; e < NEXP; ++e) p[e] *= inv;
    float w[NEXP], wsum = 0.f;
    for (int e = 0; e < NEXP; ++e) {
      int cnt = 0;
      for (int j = 0; j < NEXP; ++j) cnt += (p[j] > p[e]) || (p[j] == p[e] && j < e);
      w[e] = (cnt < 5) ? p[e] : 0.f;   // top-5 of 8
      wsum += w[e];
    }
    const float inv2 = 1.f / (wsum + 1e-8f);
    for (int e = 0; e < NEXP; ++e) wgt[(size_t)b * NEXP + e] = w[e] * inv2;
  }
}

// ---------------------------------------------------------------------------
__global__ void cvt_bf16(const float* __restrict__ src, u16* __restrict__ dst, int n) {
  const int i = (blockIdx.x * 256 + threadIdx.x) * 8;
  if (i >= n) return;
  const f32x4 a = *(const f32x4*)(src + i);
  const f32x4 b = *(const f32x4*)(src + i + 4);
  u16x8 o;
  o[0] = f2bf(a[0]); o[1] = f2bf(a[1]); o[2] = f2bf(a[2]); o[3] = f2bf(a[3]);
  o[4] = f2bf(b[0]); o[5] = f2bf(b[1]); o[6] = f2bf(b[2]); o[7] = f2bf(b[3]);
  *(u16x8*)(dst + i) = o;
}

// ---------------------------------------------------------------------------
__global__ void transpose_cvt(const float* __restrict__ src, u16* __restrict__ dst,
                              int C, int ldd, size_t src_slice,
                              size_t dst_hi, size_t dst_lo) {
  __shared__ float ts[32][33];
  const int z = blockIdx.z;
  const float* s = src + (size_t)z * src_slice;
  u16* d = dst + (size_t)(z >> 2) * dst_hi + (size_t)(z & 3) * dst_lo;
  const int c0 = blockIdx.x * 32, r0 = blockIdx.y * 32;
  const int tc = threadIdx.x & 31, tr = threadIdx.x >> 5;
#pragma unroll
  for (int p = 0; p < 4; ++p)
    ts[tr + p * 8][tc] = s[(size_t)(r0 + tr + p * 8) * C + c0 + tc];
  __syncthreads();
#pragma unroll
  for (int p = 0; p < 4; ++p) {
    const int cl = tr + p * 8;
    d[(size_t)(c0 + cl) * ldd + r0 + tc] = f2bf(ts[tc][cl]);
  }
}

// ---------------------------------------------------------------------------
// 256x256 8-phase GEMM (m201 template, plain HIP): C = A[M,K] * Bt[N,K]^T.
// 512 thr = 8 waves (2M x 4N), per-wave 128x64 out, BK=64, dbuf LDS 128KB,
// st_16x32 swizzle (linear LDS dest + pre-swizzled global src + swz read),
// counted vmcnt(4) steady / vmcnt(0) tail, setprio around MFMA clusters.
// LDS layout per 256x64 tile: 32 chunks of 1024B; chunk = (R>>4)*2 + (Cb>>6);
// in-chunk = (R&15)*64 + (Cb&63); swizzle: byte ^= ((byte>>9)&1)<<5.
template <int MH>
__device__ __forceinline__ void rdA(i32x4 rA[4][2], const char* base, int wr, int roff) {
#pragma unroll
  for (int m = 0; m < 4; ++m)
#pragma unroll
    for (int kk = 0; kk < 2; ++kk)
      rA[m][kk] = *(const i32x4*)(base + (((wr * 8 + MH * 4 + m) * 2 + kk) << 10) + roff);
}
template <int NH>
__device__ __forceinline__ void rdB(i32x4 rB[2][2], const char* base, int wc, int roff) {
#pragma unroll
  for (int n = 0; n < 2; ++n)
#pragma unroll
    for (int kk = 0; kk < 2; ++kk)
      rB[n][kk] = *(const i32x4*)(base + (((wc * 4 + NH * 2 + n) * 2 + kk) << 10) + roff);
}
template <int MH, int NH>
__device__ __forceinline__ void mm16(f32x4 acc[8][4], const i32x4 rA[4][2],
                                     const i32x4 rB[2][2]) {
  __builtin_amdgcn_s_setprio(1);
#pragma unroll
  for (int m = 0; m < 4; ++m)
#pragma unroll
    for (int n = 0; n < 2; ++n)
#pragma unroll
      for (int kk = 0; kk < 2; ++kk)
        acc[MH * 4 + m][NH * 2 + n] = __builtin_amdgcn_mfma_f32_16x16x32_bf16(
            __builtin_bit_cast(bf16x8, rA[m][kk]),
            __builtin_bit_cast(bf16x8, rB[n][kk]),
            acc[MH * 4 + m][NH * 2 + n], 0, 0, 0);
  __builtin_amdgcn_s_setprio(0);
}

template <int EPI>
__global__ __launch_bounds__(512, 2) void gemm256(
    const u16* __restrict__ A0, int lda,
    const u16* __restrict__ Bt0, int ldb, int K,
    u16* __restrict__ dstH0, Ptr4 parts,
    const float* __restrict__ wgt, const float* __restrict__ bias0, int camp) {
  __shared__ __align__(16) u16 sA[2][16384];
  __shared__ __align__(16) u16 sB[2][16384];

  const int tid = threadIdx.x;
  const int w = tid >> 6, lane = tid & 63;
  const int l15 = lane & 15, lh = lane >> 4;
  const int wr = w >> 2, wc = w & 3;               // 2(M) x 4(N) waves
  const int bN = blockIdx.x * 256, bM = blockIdx.y * 256;
  const int z = blockIdx.z;

  const u16* A = A0;
  const u16* Bt = Bt0;
  const float* bias = bias0;
  u16* dstH = dstH0;
  int expert = 0;
  if (EPI == 0) {
    expert = camp * 4 + z;
    Bt = Bt0 + (size_t)expert * DH * DIN;
    bias = bias0 + (size_t)expert * DH;
    dstH = dstH0 + (size_t)z * DH;
  } else {
    A = A0 + (size_t)z * DH;
    Bt = Bt0 + (size_t)z * DH;
  }

  // --- staging source coords (pre-swizzled: involution on byte-bit5) ---
  const int lp = lane ^ ((lane & 32) >> 4);        // flip bit1 when bit5 set
  const int grow = (w >> 1) * 16 + (lp >> 2);      // row within 64-row chunk
  const int gcol = (w & 1) * 32 + (lp & 3) * 8;    // col element within 64
  const u16* pA = A + (size_t)(bM + grow) * lda + gcol;
  const u16* pB = Bt + (size_t)(bN + grow) * ldb + gcol;
  u16* dA0 = &sA[0][w * 512];
  u16* dA1 = &sA[1][w * 512];
  u16* dB0 = &sB[0][w * 512];
  u16* dB1 = &sB[1][w * 512];

  // --- swizzled read offset within a chunk ---
  const int roff = l15 * 64 + ((lh * 16) ^ ((l15 & 8) << 2));
  const char* cA0 = (const char*)&sA[0][0];
  const char* cA1 = (const char*)&sA[1][0];
  const char* cB0 = (const char*)&sB[0][0];
  const char* cB1 = (const char*)&sB[1][0];

  const int NT = K >> 6;
  f32x4 acc[8][4] = {};
  i32x4 rA[4][2], rB0[2][2], rB1[2][2];

  // --- prologue: tile0 {B0,B1,A0,A1} + tile1 {B0,B1}; wait tile0; barrier ---
  ST2(dB0, pB, ldb);
  ST2(dB0 + 8192, pB + (size_t)128 * ldb, ldb);
  ST2(dA0, pA, lda);
  ST2(dA0 + 8192, pA + (size_t)128 * lda, lda);
  ST2(dB1, pB + 64, ldb);
  ST2(dB1 + 8192, pB + 64 + (size_t)128 * ldb, ldb);
  VM4();
  BAR();

#define TILE(T, CA, CB_, DA_OT, DB_CB)                                         \
  {                                                                            \
    const int t_ = (T);                                                        \
    const bool g1 = (t_ + 1) < NT, g2 = (t_ + 2) < NT;                         \
    const u16* pAk = pA + (t_ + 1) * 64;                                       \
    const u16* pBk = pB + (t_ + 2) * 64;                                       \
    /* ph1 */                                                                  \
    rdA<0>(rA, CA, wr, roff);                                                  \
    rdB<0>(rB0, CB_, wc, roff);                                                \
    if (g1) ST2(DA_OT, pAk, lda);                                              \
    BAR();                                                                     \
    mm16<0, 0>(acc, rA, rB0);                                                  \
    BAR();                                                                     \
    /* ph2 */                                                                  \
    rdB<1>(rB1, CB_, wc, roff);                                                \
    if (g1) ST2(DA_OT + 8192, pAk + (size_t)128 * lda, lda);                   \
    BAR();                                                                     \
    mm16<0, 1>(acc, rA, rB1);                                                  \
    BAR();                                                                     \
    /* ph3: B region of current buf is dead now -> stage tile T+2's B there */ \
    rdA<1>(rA, CA, wr, roff);                                                  \
    if (g2) ST2(DB_CB, pBk, ldb);                                              \
    BAR();                                                                     \
    mm16<1, 1>(acc, rA, rB1);                                                  \
    BAR();                                                                     \
    /* ph4 */                                                                  \
    if (g2) {                                                                  \
      ST2(DB_CB + 8192, pBk + (size_t)128 * ldb, ldb);                         \
      BAR();                                                                   \
      mm16<1, 0>(acc, rA, rB0);                                                \
      VM4();                                                                   \
    } else {                                                                   \
      BAR();                                                                   \
      mm16<1, 0>(acc, rA, rB0);                                                \
      VM0();                                                                   \
    }                                                                          \
    BAR();                                                                     \
  }

  for (int t = 0; t < NT; t += 2) {
    TILE(t, cA0, cB0, dA1, dB0);
    TILE(t + 1, cA1, cB1, dA0, dB1);
  }
#undef TILE

  // --- epilogue. C/D: col = l15, row = lh*4 + r [m89-verified] ---
  if (EPI == 0) {
#pragma unroll
    for (int m = 0; m < 8; ++m)
#pragma unroll
      for (int r = 0; r < 4; ++r) {
        const int row = bM + wr * 128 + m * 16 + lh * 4 + r;
        const float wsc = wgt[(size_t)row * NEXP + expert];
#pragma unroll
        for (int n = 0; n < 4; ++n) {
          const int col = bN + wc * 64 + n * 16 + l15;
          float v = acc[m][n][r] + bias[col];
          v = fmaxf(v, 0.0f) * wsc;
          dstH[(size_t)row * (4 * DH) + col] = f2bf(v);
        }
      }
  } else {
    float* __restrict__ P = parts.p[z];
#pragma unroll
    for (int m = 0; m < 8; ++m)
#pragma unroll
      for (int r = 0; r < 4; ++r) {
        const int row = bM + wr * 128 + m * 16 + lh * 4 + r;
#pragma unroll
        for (int n = 0; n < 4; ++n) {
          const int col = bN + wc * 64 + n * 16 + l15;
          P[(size_t)row * DOUT + col] = acc[m][n][r];
        }
      }
  }
}

// ---------------------------------------------------------------------------
__global__ void reduce_kernel(float* __restrict__ dst,
                              const float* __restrict__ p0, const float* __restrict__ p1,
                              const float* __restrict__ p2, const float* __restrict__ p3,
                              const float* __restrict__ wgt,
                              const float* __restrict__ b2c, int camp) {
  const int b = blockIdx.x, t = threadIdx.x;
  const f32x4 wv = *(const f32x4*)(wgt + (size_t)b * NEXP + camp * 4);
  const size_t ro = (size_t)b * DOUT;
#pragma unroll
  for (int j = 0; j < 4; ++j) {
    const int i = j * 256 + t;
    const float bias = wv[0] * b2c[i] + wv[1] * b2c[DOUT + i] +
                       wv[2] * b2c[2 * DOUT + i] + wv[3] * b2c[3 * DOUT + i];
    dst[ro + i] = p0[ro + i] + p1[ro + i] + p2[ro + i] + p3[ro + i] + bias;
  }
}

// ---------------------------------------------------------------------------
__global__ void final_kernel(float* __restrict__ out,
                             const float* __restrict__ alpha,
                             const float* __restrict__ beta) {
  const int b = blockIdx.x, t = threadIdx.x;
  const float* pa = out + (size_t)BATCH * DOUT + (size_t)b * DOUT;
  const float* pg = out + (size_t)2 * BATCH * DOUT + (size_t)b * DOUT;
  float* po = out + (size_t)b * DOUT;
  float d[4], s1 = 0.f, s2 = 0.f;
#pragma unroll
  for (int j = 0; j < 4; ++j) {
    const int i = j * 256 + t;
    d[j] = pa[i] - pg[i];
    s1 += d[j];
    s2 += d[j] * d[j];
  }
#pragma unroll
  for (int off = 32; off; off >>= 1) {
    s1 += __shfl_xor(s1, off);
    s2 += __shfl_xor(s2, off);
  }
  __shared__ float r1[4], r2[4];
  if ((t & 63) == 0) { r1[t >> 6] = s1; r2[t >> 6] = s2; }
  __syncthreads();
  s1 = r1[0] + r1[1] + r1[2] + r1[3];
  s2 = r2[0] + r2[1] + r2[2] + r2[3];
  const float mean = s1 * (1.f / DOUT);
  const float var = s2 * (1.f / DOUT) - mean * mean;  // population var
  const float dist = sqrtf(s2) * (1.f + var);
  const float zz = alpha[0] * dist + beta[0];
  const float corr = 2.f / (1.f + expf(-zz));
#pragma unroll
  for (int j = 0; j < 4; ++j) po[j * 256 + t] = d[j] * corr;
}

// ---------------------------------------------------------------------------
extern "C" void kernel_launch(void* const* d_in, const int* in_sizes, int n_in,
                              void* d_out, int out_size, void* d_ws, size_t ws_size,
                              hipStream_t stream) {
  const float* x   = (const float*)d_in[0];
  const float* gw  = (const float*)d_in[1];
  const float* gb  = (const float*)d_in[2];
  const float* w1  = (const float*)d_in[3];
  const float* b1  = (const float*)d_in[4];
  const float* w2  = (const float*)d_in[5];
  const float* b2  = (const float*)d_in[6];
  const float* pha = (const float*)d_in[7];
  const float* phb = (const float*)d_in[8];
  float* out = (float*)d_out;  // [output | out_a | out_g], each BATCH*DOUT f32
  float* out_a = out + (size_t)BATCH * DOUT;
  float* out_g = out + (size_t)2 * BATCH * DOUT;

  // Workspace: wgt 128KB | xb 8MB | w1t 64MB (first 32MB reused as w2t1)
  //            | w2t0 32MB | P0 16MB | P1 16MB | Hs 128MB
  char* ws = (char*)d_ws;
  float* wgt = (float*)ws;
  u16* xb   = (u16*)(ws + 131072);
  u16* w1t  = (u16*)(ws + 8519680);
  u16* w2t1 = w1t;  // recycled after camp0 layer-1
  u16* w2t0 = (u16*)(ws + 75628544);
  float* P0 = (float*)(ws + 109182976);
  float* P1 = (float*)(ws + 125960192);
  u16* Hs   = (u16*)(ws + 142737408);

  gate_kernel<<<BATCH / 4, 256, 0, stream>>>(x, gw, gb, wgt);
  cvt_bf16<<<(BATCH * DIN / 8) / 256, 256, 0, stream>>>(x, xb, BATCH * DIN);
  transpose_cvt<<<dim3(DH / 32, DIN / 32, NEXP), 256, 0, stream>>>(
      w1, w1t, DH, DIN, (size_t)DIN * DH, (size_t)4 * DH * DIN, (size_t)DH * DIN);
  transpose_cvt<<<dim3(DOUT / 32, DH / 32, 4), 256, 0, stream>>>(
      w2, w2t0, DOUT, 4 * DH, (size_t)DH * DOUT, 0, (size_t)DH);

  Ptr4 parts0 = {{out_a, out, out_g, P0}};
  Ptr4 parts1 = {{out_g, out, P0, P1}};
  Ptr4 dummy = {{nullptr, nullptr, nullptr, nullptr}};

  // ---- camp 0 ----
  gemm256<0><<<dim3(DH / 256, BATCH / 256, 4), 512, 0, stream>>>(
      xb, DIN, w1t, DIN, DIN, Hs, dummy, wgt, b1, 0);
  transpose_cvt<<<dim3(DOUT / 32, DH / 32, 4), 256, 0, stream>>>(
      w2 + (size_t)4 * DH * DOUT, w2t1, DOUT, 4 * DH, (size_t)DH * DOUT, 0, (size_t)DH);
  gemm256<2><<<dim3(DOUT / 256, BATCH / 256, 4), 512, 0, stream>>>(
      Hs, 4 * DH, w2t0, 4 * DH, DH, nullptr, parts0, nullptr, nullptr, 0);
  reduce_kernel<<<BATCH, 256, 0, stream>>>(out_a, out_a, out, out_g, P0,
                                           wgt, b2, 0);
  // ---- camp 1 ----
  gemm256<0><<<dim3(DH / 256, BATCH / 256, 4), 512, 0, stream>>>(
      xb, DIN, w1t, DIN, DIN, Hs, dummy, wgt, b1, 1);
  gemm256<2><<<dim3(DOUT / 256, BATCH / 256, 4), 512, 0, stream>>>(
      Hs, 4 * DH, w2t1, 4 * DH, DH, nullptr, parts1, nullptr, nullptr, 1);
  reduce_kernel<<<BATCH, 256, 0, stream>>>(out_g, out_g, out, P0, P1,
                                           wgt, b2 + (size_t)4 * DOUT, 1);

  final_kernel<<<BATCH, 256, 0, stream>>>(out, pha, phb);
}